// Round 5
// baseline (80.342 us; speedup 1.0000x reference)
//
#include <hip/hip_runtime.h>
#include <math.h>

#define N_AGENTS 1024
#define HIDDEN   128
#define GRIDSZ   32
#define NCELLS   1024
#define KDIM     2048

typedef __attribute__((ext_vector_type(8))) short short8;   // 8 bf16 = 4 VGPRs
typedef __attribute__((ext_vector_type(4))) float floatx4;  // MFMA accumulator

static __device__ __forceinline__ ushort f2bf(float x) {   // RNE fp32->bf16
    union { float f; unsigned u; } v; v.f = x;
    return (ushort)((v.u + 0x7fffu + ((v.u >> 16) & 1u)) >> 16);
}

// One block = (m-tile of 16 agents) x (n-group of 32 cols). Fully self-contained:
// Sh table from hidden, winner scan, pooling -> LDS bf16 A-tile, MFMA vs W
// (fp32->bf16 in-register), direct out store with bias. No inter-block deps.
__global__ __launch_bounds__(512, 2) void k_fused(
        const float* __restrict__ hidden, const float* __restrict__ obs2,
        const float* __restrict__ W, const float* __restrict__ bias,
        float* __restrict__ out) {
    __shared__ float2 spos[N_AGENTS];                   // 8 KB
    __shared__ float4 ssh[N_AGENTS];                    // 16 KB
    __shared__ int win[16][NCELLS];                     // 64 KB (reused as pbuf)
    __shared__ __align__(16) ushort Gs[256 * 16 * 8];   // 64 KB: [kblk][row][8] bf16

    const int tid = threadIdx.x;
    const int mt = blockIdx.x >> 2;      // 64 m-tiles
    const int ng = blockIdx.x & 3;       // 4 n-groups of 32 cols
    const int ibase = mt * 16;

    // ---- P0: positions, Sh table (all 1024 agents), winner-grid init
    const float2* o2 = (const float2*)obs2;
    spos[tid] = o2[tid];
    spos[tid + 512] = o2[tid + 512];
#pragma unroll
    for (int q = 0; q < 8; ++q) {
        int idx = q * 512 + tid;          // entry (j, c)
        int j = idx >> 2, c = idx & 3;
        const float* h = hidden + j * HIDDEN + c * 8;
        float s = 0.f;
#pragma unroll
        for (int u = 0; u < 4; ++u) {     // Sh[j][c] = sum of 32 strided floats
            float4 a = *(const float4*)(h + u * 32);
            float4 b = *(const float4*)(h + u * 32 + 4);
            s += a.x + a.y + a.z + a.w + b.x + b.y + b.z + b.w;
        }
        ((float*)&ssh[j])[c] = s;
    }
    {
        int* wl = &win[0][0];
#pragma unroll
        for (int q = 0; q < 32; ++q) wl[q * 512 + tid] = -1;
    }
    __syncthreads();

    // ---- P1: one j-scan fills 16 winner grids (set semantics == max j)
    float2 pi[16];
#pragma unroll
    for (int a = 0; a < 16; ++a) pi[a] = spos[ibase + a];
#pragma unroll
    for (int half = 0; half < 2; ++half) {
        int jj = half * 512 + tid;
        float2 pj = spos[jj];
        if (!isnan(pj.x)) {
#pragma unroll
            for (int a = 0; a < 16; ++a) {
                if (jj == ibase + a) continue;
                // exact reference fp32 math: /0.125 == *8 (exact pow2), then +16
                float rx = (pj.x - pi[a].x) * 8.0f + 16.0f;   // NaN pi -> cmps false
                float ry = (pj.y - pi[a].y) * 8.0f + 16.0f;
                if (rx >= 0.f && rx < 32.f && ry >= 0.f && ry < 32.f)
                    atomicMax(&win[a][(int)rx * GRIDSZ + (int)ry], jj);
            }
        }
    }
    __syncthreads();

    // ---- P2: pooling -> bf16 A-tile in LDS, layout [kblk=k/8][row=a][8 elems]
#pragma unroll
    for (int q = 0; q < 16; ++q) {
        int task = q * 512 + tid;
        int a = task & 15, p = task >> 4;   // cell-pair p, local agent a
        int w0 = win[a][2 * p], w1 = win[a][2 * p + 1];
        float4 v = {0.f, 0.f, 0.f, 0.f};
        if (w0 >= 0) { float4 s = ssh[w0]; v.x += s.x; v.y += s.y; v.z += s.z; v.w += s.w; }
        if (w1 >= 0) { float4 s = ssh[w1]; v.x += s.x; v.y += s.y; v.z += s.z; v.w += s.w; }
        ushort4 u;
        u.x = f2bf(v.x); u.y = f2bf(v.y); u.z = f2bf(v.z); u.w = f2bf(v.w);
        // k = 4p + [0..3]  ->  kblk = p>>1, e = (p&1)*4 + [0..3]
        *(ushort4*)(Gs + ((p >> 1) * 16 + a) * 8 + (p & 1) * 4) = u;
    }
    __syncthreads();

    // ---- P3: MFMA. wave (ntl, ks): 16x16 out tile at (mt*16, ng*32+ntl*16),
    // k-split ks*512..+511. A from LDS Gs; B = W fp32 from L2, cvt in-register.
    const int wv = tid >> 6, lane = tid & 63;
    const int ntl = wv >> 2, ks = wv & 3;
    const int r16 = lane & 15, quad = lane >> 4;
    const int col = ng * 32 + ntl * 16 + r16;
    const float* Wp = W + (size_t)col * KDIM + ks * 512 + quad * 8;
    floatx4 acc = {0.f, 0.f, 0.f, 0.f};
#pragma unroll
    for (int kb = 0; kb < 16; ++kb) {
        short8 av = *(const short8*)(Gs + ((ks * 64 + kb * 4 + quad) * 16 + r16) * 8);
        float4 wa = *(const float4*)(Wp + kb * 32);
        float4 wb = *(const float4*)(Wp + kb * 32 + 4);
        short8 bv;
        bv[0] = (short)f2bf(wa.x); bv[1] = (short)f2bf(wa.y);
        bv[2] = (short)f2bf(wa.z); bv[3] = (short)f2bf(wa.w);
        bv[4] = (short)f2bf(wb.x); bv[5] = (short)f2bf(wb.y);
        bv[6] = (short)f2bf(wb.z); bv[7] = (short)f2bf(wb.w);
        acc = __builtin_amdgcn_mfma_f32_16x16x32_bf16(av, bv, acc, 0, 0, 0);
    }

    // ---- P4: reduce the 4 k-splits (pbuf aliases dead win), add bias, store.
    float* pbuf = (float*)&win[0][0];   // 8 KB used
    *(floatx4*)&pbuf[tid * 4] = acc;
    __syncthreads();
    if (ks == 0) {
#pragma unroll
        for (int ksi = 1; ksi < 4; ++ksi) {
            floatx4 pv = *(const floatx4*)&pbuf[((wv + ksi) * 64 + lane) * 4];
            acc[0] += pv[0]; acc[1] += pv[1]; acc[2] += pv[2]; acc[3] += pv[3];
        }
        float bc = bias[col];
        // C/D layout (m89-verified): col = lane&15, row = quad*4 + reg
#pragma unroll
        for (int r = 0; r < 4; ++r)
            out[(size_t)(ibase + quad * 4 + r) * HIDDEN + col] = acc[r] + bc;
    }
}

extern "C" void kernel_launch(void* const* d_in, const int* in_sizes, int n_in,
                              void* d_out, int out_size, void* d_ws, size_t ws_size,
                              hipStream_t stream) {
    const float* hidden = (const float*)d_in[0];
    // d_in[1] = obs1 — unused by the reference
    const float* obs2   = (const float*)d_in[2];
    const float* W      = (const float*)d_in[3];
    const float* b      = (const float*)d_in[4];
    float* out = (float*)d_out;
    (void)d_ws; (void)ws_size;

    k_fused<<<256, 512, 0, stream>>>(hidden, obs2, W, b, out);
}

// Round 6
// 75.075 us; speedup vs baseline: 1.0702x; 1.0702x over previous
//
#include <hip/hip_runtime.h>
#include <math.h>

#define N_AGENTS 1024
#define HIDDEN   128
#define GRIDSZ   32
#define NCELLS   1024
#define KDIM     2048

typedef __attribute__((ext_vector_type(8))) short short8;   // 8 bf16 = 4 VGPRs
typedef __attribute__((ext_vector_type(4))) float floatx4;  // MFMA accumulator

static __device__ __forceinline__ ushort f2bf(float x) {   // RNE fp32->bf16
    union { float f; unsigned u; } v; v.f = x;
    return (ushort)((v.u + 0x7fffu + ((v.u >> 16) & 1u)) >> 16);
}

// K1 (one-time, GPU-wide): Sh table from hidden (read once), Wb = bf16(W).
__global__ __launch_bounds__(256) void k_prep(const float* __restrict__ hidden,
                                              const float* __restrict__ W,
                                              float* __restrict__ Sh,
                                              ushort* __restrict__ Wb) {
    int gt = blockIdx.x * 256 + threadIdx.x;   // 65536 threads
    {   // W: 262144 elems, 4 per thread (layout-preserving row-major cvt)
        float4 w = ((const float4*)W)[gt];
        ushort4 u;
        u.x = f2bf(w.x); u.y = f2bf(w.y); u.z = f2bf(w.z); u.w = f2bf(w.w);
        *(ushort4*)(Wb + (size_t)gt * 4) = u;
    }
    if (gt < N_AGENTS * 4) {   // Sh[j][c] = sum over d with ((d>>3)&3)==c of hidden[j][d]
        int j = gt >> 2, c = gt & 3;
        const float* h = hidden + j * HIDDEN + c * 8;
        float s = 0.f;
#pragma unroll
        for (int u = 0; u < 4; ++u) {
            float4 a = *(const float4*)(h + u * 32);
            float4 b = *(const float4*)(h + u * 32 + 4);
            s += a.x + a.y + a.z + a.w + b.x + b.y + b.z + b.w;
        }
        Sh[gt] = s;
    }
}

// K2: block = (m-tile of 16 agents) x (n-group of 32 cols). Winner scan,
// pooling -> LDS bf16 A-tile, MFMA vs bf16 W from L2, direct store with bias.
__global__ __launch_bounds__(512, 2) void k_main(
        const float* __restrict__ obs2, const float4* __restrict__ Sh4,
        const ushort* __restrict__ Wb, const float* __restrict__ bias,
        float* __restrict__ out) {
    __shared__ float2 spos[N_AGENTS];                   // 8 KB
    __shared__ float4 ssh[N_AGENTS];                    // 16 KB
    __shared__ int win[16][NCELLS];                     // 64 KB (reused as pbuf)
    __shared__ __align__(16) ushort Gs[256 * 16 * 8];   // 64 KB: [kblk][row][8] bf16

    const int tid = threadIdx.x;
    const int mt = blockIdx.x >> 2;      // 64 m-tiles
    const int ng = blockIdx.x & 3;       // 4 n-groups of 32 cols
    const int ibase = mt * 16;

    // ---- P0: stage positions + Sh, init winner grids
    const float2* o2 = (const float2*)obs2;
    spos[tid] = o2[tid];
    spos[tid + 512] = o2[tid + 512];
    ssh[tid] = Sh4[tid];
    ssh[tid + 512] = Sh4[tid + 512];
    {
        int4* wl = (int4*)&win[0][0];
        int4 m1 = {-1, -1, -1, -1};
#pragma unroll
        for (int q = 0; q < 8; ++q) wl[q * 512 + tid] = m1;
    }
    __syncthreads();

    // ---- P1: one j-scan fills 16 winner grids (set semantics == max j)
    float2 pi[16];
#pragma unroll
    for (int a = 0; a < 16; ++a) pi[a] = spos[ibase + a];
#pragma unroll
    for (int half = 0; half < 2; ++half) {
        int jj = half * 512 + tid;
        float2 pj = spos[jj];
        if (!isnan(pj.x)) {
#pragma unroll
            for (int a = 0; a < 16; ++a) {
                if (jj == ibase + a) continue;
                // exact reference fp32 math: /0.125 == *8 (exact pow2), then +16
                float rx = (pj.x - pi[a].x) * 8.0f + 16.0f;   // NaN pi -> cmps false
                float ry = (pj.y - pi[a].y) * 8.0f + 16.0f;
                if (rx >= 0.f && rx < 32.f && ry >= 0.f && ry < 32.f)
                    atomicMax(&win[a][(int)rx * GRIDSZ + (int)ry], jj);
            }
        }
    }
    __syncthreads();

    // ---- P2: pooling -> bf16 A-tile in LDS, layout [kblk=k/8][row=a][8 elems]
#pragma unroll
    for (int q = 0; q < 16; ++q) {
        int task = q * 512 + tid;
        int a = task & 15, p = task >> 4;   // cell-pair p, local agent a
        int w0 = win[a][2 * p], w1 = win[a][2 * p + 1];
        float4 v = {0.f, 0.f, 0.f, 0.f};
        if (w0 >= 0) { float4 s = ssh[w0]; v.x += s.x; v.y += s.y; v.z += s.z; v.w += s.w; }
        if (w1 >= 0) { float4 s = ssh[w1]; v.x += s.x; v.y += s.y; v.z += s.z; v.w += s.w; }
        ushort4 u;
        u.x = f2bf(v.x); u.y = f2bf(v.y); u.z = f2bf(v.z); u.w = f2bf(v.w);
        // k = 4p + [0..3]  ->  kblk = p>>1, e = (p&1)*4 + [0..3]
        *(ushort4*)(Gs + ((p >> 1) * 16 + a) * 8 + (p & 1) * 4) = u;
    }
    __syncthreads();

    // ---- P3: MFMA. wave (ntl, ks): 16x16 out tile at (mt*16, ng*32+ntl*16),
    // k-split ks*512..+511. A from LDS Gs, B = bf16 W straight from L2.
    const int wv = tid >> 6, lane = tid & 63;
    const int ntl = wv >> 2, ks = wv & 3;
    const int r16 = lane & 15, quad = lane >> 4;
    const int col = ng * 32 + ntl * 16 + r16;
    const ushort* Wp = Wb + (size_t)col * KDIM + ks * 512 + quad * 8;
    floatx4 acc = {0.f, 0.f, 0.f, 0.f};
#pragma unroll
    for (int kb = 0; kb < 16; ++kb) {
        short8 av = *(const short8*)(Gs + ((ks * 64 + kb * 4 + quad) * 16 + r16) * 8);
        short8 bv = *(const short8*)(Wp + kb * 32);
        acc = __builtin_amdgcn_mfma_f32_16x16x32_bf16(av, bv, acc, 0, 0, 0);
    }

    // ---- P4: reduce the 4 k-splits (pbuf aliases dead win), add bias, store.
    __syncthreads();   // win reads done before realias
    float* pbuf = (float*)&win[0][0];   // 8 KB used
    *(floatx4*)&pbuf[tid * 4] = acc;
    __syncthreads();
    if (ks == 0) {
#pragma unroll
        for (int ksi = 1; ksi < 4; ++ksi) {
            floatx4 pv = *(const floatx4*)&pbuf[((wv + ksi) * 64 + lane) * 4];
            acc[0] += pv[0]; acc[1] += pv[1]; acc[2] += pv[2]; acc[3] += pv[3];
        }
        float bc = bias[col];
        // C/D layout (m89-verified): col = lane&15, row = quad*4 + reg
#pragma unroll
        for (int r = 0; r < 4; ++r)
            out[(size_t)(ibase + quad * 4 + r) * HIDDEN + col] = acc[r] + bc;
    }
}

extern "C" void kernel_launch(void* const* d_in, const int* in_sizes, int n_in,
                              void* d_out, int out_size, void* d_ws, size_t ws_size,
                              hipStream_t stream) {
    const float* hidden = (const float*)d_in[0];
    // d_in[1] = obs1 — unused by the reference
    const float* obs2   = (const float*)d_in[2];
    const float* W      = (const float*)d_in[3];
    const float* b      = (const float*)d_in[4];
    float* out = (float*)d_out;

    float*  Sh = (float*) d_ws;                       // 16 KB
    ushort* Wb = (ushort*)((char*)d_ws + 65536);      // 512 KB bf16 W

    k_prep<<<256, 256, 0, stream>>>(hidden, W, Sh, Wb);
    k_main<<<256, 512, 0, stream>>>(obs2, (const float4*)Sh, Wb, b, out);
}